// Round 5
// baseline (518.542 us; speedup 1.0000x reference)
//
#include <hip/hip_runtime.h>
#include <hip/hip_bf16.h>

#define B 32
#define H 128
#define L 4096
#define NC 32
#define NL 6
#define NCHUNK 128

typedef __hip_bfloat16 bf16;
typedef __attribute__((ext_vector_type(8))) short short8v;   // 8 bf16 (4 VGPR)
typedef __attribute__((ext_vector_type(4))) float floatx4;   // MFMA C/D

__device__ __forceinline__ float b2f(bf16 v) { return __bfloat162float(v); }
__device__ __forceinline__ float bu2f(unsigned int u) {
  union { unsigned int i; float f; } v; v.i = u << 16; return v.f;
}
// float -> bf16 bits via HW RNE convert
__device__ __forceinline__ unsigned short f2bs(float f) {
  bf16 b = __float2bfloat16(f);
  union { bf16 h; unsigned short s; } cv; cv.h = b; return cv.s;
}
// two floats -> packed bf16 dword (a low, b high) via v_cvt_pk_bf16_f32
__device__ __forceinline__ unsigned pack2(float a, float b) {
  union { __hip_bfloat162 h; unsigned u; } cv;
  cv.h = __float22bfloat162_rn(make_float2(a, b));
  return cv.u;
}

// Branch-free exact GELU: erf via Abramowitz-Stegun 7.1.26 (|eps|<=1.5e-7),
// v_rcp + v_exp instead of libm erff's divergent two-path rational (~50 slot-ops -> ~14).
__device__ __forceinline__ float gelu_exact(float v) {
  float ax = fabsf(v) * 0.70710678118654752f;                 // |v|/sqrt(2)
  float t  = __builtin_amdgcn_rcpf(fmaf(0.3275911f, ax, 1.f));
  float p  = t * fmaf(t, fmaf(t, fmaf(t, fmaf(t, 1.061405429f, -1.453152027f),
                                      1.421413741f), -0.284496736f), 0.254829592f);
  float e  = __builtin_amdgcn_exp2f(ax * ax * -1.4426950408889634f);  // exp(-x^2)
  float er = fmaf(-p, e, 1.f);                                // erf(|x|)
  return v * fmaf(0.5f, copysignf(er, v), 0.5f);              // v*0.5*(1+erf(v/sqrt2))
}

// ---------------- encoder (R2: float4 loads + packed bf16 uint4 stores;
// R3: zero-init pooled[blk] — blockIdx maps 1:1 to pooled index) ----------------
__global__ void encoder_kernel(const float* __restrict__ x, const float* __restrict__ enc_W,
                               const float* __restrict__ enc_b, bf16* __restrict__ h,
                               float* __restrict__ pooled) {
  int blk = blockIdx.x;
  int b = blk >> 7, ch = blk & 127;
  if (threadIdx.x == 0) pooled[blk] = 0.f;   // (b*H+ch) == blk
  float w0 = enc_W[ch];
  float w1 = enc_W[H + ch];
  float bb = enc_b[ch];
  const float4* x0 = (const float4*)(x + (size_t)b * 2 * L);
  const float4* x1 = (const float4*)(x + (size_t)b * 2 * L + L);
  uint4* out = (uint4*)(h + ((size_t)b * H + ch) * L);
  for (int i = threadIdx.x; i < L / 8; i += blockDim.x) {
    float4 a0 = x0[2 * i], a1 = x0[2 * i + 1];
    float4 c0 = x1[2 * i], c1 = x1[2 * i + 1];
    unsigned q0 = pack2(fmaf(a0.x, w0, fmaf(c0.x, w1, bb)), fmaf(a0.y, w0, fmaf(c0.y, w1, bb)));
    unsigned q1 = pack2(fmaf(a0.z, w0, fmaf(c0.z, w1, bb)), fmaf(a0.w, w0, fmaf(c0.w, w1, bb)));
    unsigned q2 = pack2(fmaf(a1.x, w0, fmaf(c1.x, w1, bb)), fmaf(a1.y, w0, fmaf(c1.y, w1, bb)));
    unsigned q3 = pack2(fmaf(a1.z, w0, fmaf(c1.z, w1, bb)), fmaf(a1.w, w0, fmaf(c1.w, w1, bb)));
    out[i] = make_uint4(q0, q1, q2, q3);
  }
}

// Wb[l][hl][o][k]: hi/lo bf16 split of out_W[l][o][k]; per-layer stride 65536
__global__ void w_prep_kernel(const float* __restrict__ out_W, unsigned short* __restrict__ Wb) {
  int idx = blockIdx.x * 256 + threadIdx.x;
  if (idx >= NL * 2 * H * H) return;
  int l = idx / (2 * H * H);
  int rem = idx % (2 * H * H);
  float v = out_W[idx];
  unsigned short hi = f2bs(v);
  unsigned short lo = f2bs(v - bu2f(hi));
  Wb[(size_t)l * 65536 + rem] = hi;
  Wb[(size_t)l * 65536 + 32768 + rem] = lo;
}

// ---------------- per-(layer,h) B-matrix precompute: ALL LAYERS IN ONE DISPATCH ----
// R1: all VT/KT/WT entries are Re/Im of w_n^k (or cd_n*w_n^k). Compute w_n once via
// libm (32 threads), build LDS power table P[n][k]=w^k by 31 complex muls, then the
// 5120 bulk entries are LDS reads + cmul — zero transcendentals in the bulk loops.
__global__ __launch_bounds__(256) void s4d_prep_all_kernel(
    const float* __restrict__ log_dt, const float* __restrict__ C_re,
    const float* __restrict__ C_im, const float* __restrict__ log_A_real,
    const float* __restrict__ A_imag, const float* __restrict__ Dp,
    unsigned short* __restrict__ Bg, float2* __restrict__ wTg) {
  __shared__ float2 cd_s[NC];
  __shared__ float K_s[32];
  __shared__ float2 P_s[NC][33];   // w_n^k, k=0..32 (row stride 264 B -> 2-way bank alias max)
  int lh = blockIdx.x;
  int layer = lh >> 7, h = lh & 127;
  int tid = threadIdx.x;
  if (tid < NC) {
    int n = tid, base = (layer * H + h) * NC + n;
    float dt = expf(log_dt[layer * H + h]);
    float Are = -expf(log_A_real[base]);
    float Aim = A_imag[base];
    float dre = dt * Are, dim = dt * Aim;
    float er = expf(dre);
    float wre = er * cosf(dim), wim = er * sinf(dim);
    float emre = wre - 1.f, emim = wim;   // expm1(dtA)
    float cre = C_re[base], cim = C_im[base];
    float nre = cre * emre - cim * emim, nim = cre * emim + cim * emre;
    float den = Are * Are + Aim * Aim;
    cd_s[n] = make_float2((nre * Are + nim * Aim) / den, (nim * Are - nre * Aim) / den);
    float e32 = expf(dre * 32.f);
    wTg[lh * NC + n] = make_float2(e32 * cosf(dim * 32.f), e32 * sinf(dim * 32.f));
    // power walk: P[n][k] = w^k (sequential cmul; |w|<1 so error doesn't amplify)
    P_s[n][0] = make_float2(1.f, 0.f);
    P_s[n][1] = make_float2(wre, wim);
    float rr = wre, ri = wim;
    #pragma unroll
    for (int k = 2; k <= 32; ++k) {
      float nr = rr * wre - ri * wim;
      ri = rr * wim + ri * wre;
      rr = nr;
      P_s[n][k] = make_float2(rr, ri);
    }
  }
  __syncthreads();
  if (tid < 32) {  // K[tau] = 2 sum_n Re(cd_n w_n^tau)  — table reads, conflict-free
    float acc = 0.f;
    for (int n = 0; n < NC; ++n) {
      float2 p = P_s[n][tid];
      acc += cd_s[n].x * p.x - cd_s[n].y * p.y;
    }
    K_s[tid] = 2.f * acc;
  }
  __syncthreads();
  unsigned short* bb = Bg + (size_t)lh * 12288;
  float Dv = Dp[layer * H + h];
  #pragma unroll
  for (int i = 0; i < 8; ++i) {     // VT: 2048 entries = Re/Im w^(31-t)
    int idx = tid + i * 256;
    int n2 = idx >> 5, t = idx & 31, n = n2 >> 1;
    float2 p = P_s[n][31 - t];
    float v = (n2 & 1) ? p.y : p.x;
    unsigned short hi = f2bs(v);
    unsigned short lo = f2bs(v - bu2f(hi));
    bb[n2 * 40 + t] = hi;
    bb[2560 + n2 * 40 + t] = lo;
  }
  #pragma unroll
  for (int i = 0; i < 4; ++i) {     // KT: 1024 entries
    int idx = tid + i * 256;
    int t = idx >> 5, m = idx & 31;
    float v = (m > t) ? 0.f : (K_s[t - m] + (m == t ? Dv : 0.f));
    unsigned short hi = f2bs(v);
    unsigned short lo = f2bs(v - bu2f(hi));
    bb[5120 + t * 40 + m] = hi;
    bb[6400 + t * 40 + m] = lo;
  }
  #pragma unroll
  for (int i = 0; i < 8; ++i) {     // WT: 2048 entries = ±2·{Re,Im}(cd_n w^(t+1))
    int idx = tid + i * 256;
    int t = idx >> 6, k = idx & 63, n = k >> 1;
    float2 p = P_s[n][t + 1];
    float cwr = cd_s[n].x * p.x - cd_s[n].y * p.y;
    float cwi = cd_s[n].x * p.y + cd_s[n].y * p.x;
    float v = (k & 1) ? -2.f * cwi : 2.f * cwr;
    unsigned short hi = f2bs(v);
    unsigned short lo = f2bs(v - bu2f(hi));
    bb[7680 + t * 72 + k] = hi;
    bb[9984 + t * 72 + k] = lo;
  }
}

// ---------------- S4D conv v7: no U staging (A-frags direct from global), GT/GE in
// S-row pads; LDS 37120 B -> 4 blocks/CU. Epilogue stages y through dead S_hi.
// R0: GELU via branch-free A&S erf (was libm erff — dominant VALU cost). ----------
__global__ __launch_bounds__(256, 4) void s4d_conv7_kernel(
    const bf16* __restrict__ u_g, bf16* __restrict__ y_g,
    const unsigned short* __restrict__ Bg, const float2* __restrict__ wTg) {
  static __shared__ char __align__(16) sm[37120];
  constexpr int O_SH = 0;       // scan re / packed hi: 128 rows x 144 B (cols 0..127 + 16 B pad)
  constexpr int O_SL = 18432;   // scan im / packed lo
  constexpr int O_WT = 36864;   // wT [32] float2 = 256 B
  // GT[i] lives in S_hi pad: O_SH + (i>>1)*144 + 128 + (i&1)*8   (i = g*32+n)
  // GE[i] lives in S_lo pad: O_SL + (i>>1)*144 + 128 + (i&1)*8

  int tid = threadIdx.x;
  int lane = tid & 63, wv = tid >> 6;
  int r15 = lane & 15, quad = lane >> 4;
  int bh = blockIdx.x, hh = bh & 127;
  const char* bg0 = (const char*)(Bg + (size_t)hh * 12288);
  const char* ug0 = (const char*)(u_g + (size_t)bh * L);

  if (tid < 32) *(float2*)(sm + O_WT + tid * 8) = wTg[hh * 32 + tid];

  // A-fragments direct from global (fully coalesced 16 B/lane within a 4 KB span)
  short8v aU0 = *(const short8v*)(ug0 + ((wv * 2 + 0) * 16 + r15) * 64 + quad * 16);
  short8v aU1 = *(const short8v*)(ug0 + ((wv * 2 + 1) * 16 + r15) * 64 + quad * 16);
  // V fragments from L2
  short8v bvh[4], bvl[4];
  #pragma unroll
  for (int nt = 0; nt < 4; ++nt) {
    bvh[nt] = *(const short8v*)(bg0 + 0    + (nt * 16 + r15) * 80 + quad * 16);
    bvl[nt] = *(const short8v*)(bg0 + 5120 + (nt * 16 + r15) * 80 + quad * 16);
  }

  // ---- phase P (no barrier needed before: all inputs are regs)
  floatx4 cp[2][4];
  #pragma unroll
  for (int mt = 0; mt < 2; ++mt)
    #pragma unroll
    for (int nt = 0; nt < 4; ++nt) cp[mt][nt] = (floatx4){0.f, 0.f, 0.f, 0.f};
  #pragma unroll
  for (int nt = 0; nt < 4; ++nt) {
    cp[0][nt] = __builtin_amdgcn_mfma_f32_16x16x32_bf16(aU0, bvh[nt], cp[0][nt], 0, 0, 0);
    cp[0][nt] = __builtin_amdgcn_mfma_f32_16x16x32_bf16(aU0, bvl[nt], cp[0][nt], 0, 0, 0);
    cp[1][nt] = __builtin_amdgcn_mfma_f32_16x16x32_bf16(aU1, bvh[nt], cp[1][nt], 0, 0, 0);
    cp[1][nt] = __builtin_amdgcn_mfma_f32_16x16x32_bf16(aU1, bvl[nt], cp[1][nt], 0, 0, 0);
  }
  #pragma unroll
  for (int mt = 0; mt < 2; ++mt)
    #pragma unroll
    for (int nt = 0; nt < 4; ++nt) {
      int n2 = nt * 16 + r15;
      int off = ((n2 & 1) ? O_SL : O_SH) + (n2 >> 1) * 4;
      #pragma unroll
      for (int rg = 0; rg < 4; ++rg) {
        int c = (wv * 2 + mt) * 16 + quad * 4 + rg;
        *(float*)(sm + off + c * 144) = cp[mt][nt][rg];
      }
    }
  __syncthreads();   // P stores + wT visible

  // ---- scan A: batched loads, recurrence in regs, prefixes HELD in regs
  int sg = tid >> 5, sn = tid & 31;
  float2 swt = *(const float2*)(sm + O_WT + sn * 8);
  float epr[16], epi[16];
  {
    float pr_[16], pi_[16];
    #pragma unroll
    for (int k = 0; k < 16; ++k) {
      pr_[k] = *(const float*)(sm + O_SH + (sg * 16 + k) * 144 + sn * 4);
      pi_[k] = *(const float*)(sm + O_SL + (sg * 16 + k) * 144 + sn * 4);
    }
    float rr = 0.f, ri = 0.f;
    #pragma unroll
    for (int k = 0; k < 16; ++k) {
      epr[k] = rr; epi[k] = ri;
      float nr = swt.x * rr - swt.y * ri + pr_[k];
      ri = swt.x * ri + swt.y * rr + pi_[k];
      rr = nr;
    }
    int i = sg * 32 + sn;
    *(float2*)(sm + O_SH + (i >> 1) * 144 + 128 + (i & 1) * 8) = make_float2(rr, ri);  // GT
  }
  __syncthreads();
  // ---- scan B: serial over 8 groups; wT^16 via 4 squarings
  if (tid < 32) {
    float2 wt = *(const float2*)(sm + O_WT + tid * 8);
    float w2r = wt.x * wt.x - wt.y * wt.y,   w2i = 2.f * wt.x * wt.y;
    float w4r = w2r * w2r - w2i * w2i,       w4i = 2.f * w2r * w2i;
    float w8r = w4r * w4r - w4i * w4i,       w8i = 2.f * w4r * w4i;
    float w16r = w8r * w8r - w8i * w8i,      w16i = 2.f * w8r * w8i;
    float rr = 0.f, ri = 0.f;
    for (int g = 0; g < 8; ++g) {
      int i = g * 32 + tid;
      *(float2*)(sm + O_SL + (i >> 1) * 144 + 128 + (i & 1) * 8) = make_float2(rr, ri);  // GE
      float2 gt = *(const float2*)(sm + O_SH + (i >> 1) * 144 + 128 + (i & 1) * 8);
      float nr = w16r * rr - w16i * ri + gt.x;
      ri = w16r * ri + w16i * rr + gt.y;
      rr = nr;
    }
  }
  __syncthreads();
  // ---- fixup: E[c] = prefix + wT^k * GE[g]; HW packed-cvt hi/lo write
  {
    int i = sg * 32 + sn;
    float2 ge = *(const float2*)(sm + O_SL + (i >> 1) * 144 + 128 + (i & 1) * 8);
    float ar = ge.x, ai = ge.y;   // wT^0 * GE
    #pragma unroll
    for (int k = 0; k < 16; ++k) {
      int c = sg * 16 + k;
      float er = epr[k] + ar;
      float ei = epi[k] + ai;
      unsigned uh = pack2(er, ei);
      *(unsigned*)(sm + O_SH + c * 144 + sn * 4) = uh;
      *(unsigned*)(sm + O_SL + c * 144 + sn * 4) =
          pack2(er - bu2f(uh & 0xffffu), ei - bu2f(uh >> 16));
      float nr = ar * swt.x - ai * swt.y;   // advance wT^k * GE
      ai = ar * swt.y + ai * swt.x;
      ar = nr;
    }
  }
  __syncthreads();

  // ---- Toeplitz + modal MFMAs (K/W frags direct from L2)
  floatx4 acc[2][2];
  #pragma unroll
  for (int mt = 0; mt < 2; ++mt)
    #pragma unroll
    for (int nt = 0; nt < 2; ++nt) acc[mt][nt] = (floatx4){0.f, 0.f, 0.f, 0.f};
  #pragma unroll
  for (int nt = 0; nt < 2; ++nt) {
    short8v kh = *(const short8v*)(bg0 + 10240 + (nt * 16 + r15) * 80 + quad * 16);
    short8v kl = *(const short8v*)(bg0 + 12800 + (nt * 16 + r15) * 80 + quad * 16);
    acc[0][nt] = __builtin_amdgcn_mfma_f32_16x16x32_bf16(aU0, kh, acc[0][nt], 0, 0, 0);
    acc[0][nt] = __builtin_amdgcn_mfma_f32_16x16x32_bf16(aU0, kl, acc[0][nt], 0, 0, 0);
    acc[1][nt] = __builtin_amdgcn_mfma_f32_16x16x32_bf16(aU1, kh, acc[1][nt], 0, 0, 0);
    acc[1][nt] = __builtin_amdgcn_mfma_f32_16x16x32_bf16(aU1, kl, acc[1][nt], 0, 0, 0);
  }
  #pragma unroll
  for (int ks = 0; ks < 2; ++ks) {
    short8v sh0 = *(const short8v*)(sm + O_SH + ((wv * 2 + 0) * 16 + r15) * 144 + ks * 64 + quad * 16);
    short8v sh1 = *(const short8v*)(sm + O_SH + ((wv * 2 + 1) * 16 + r15) * 144 + ks * 64 + quad * 16);
    short8v sl0 = *(const short8v*)(sm + O_SL + ((wv * 2 + 0) * 16 + r15) * 144 + ks * 64 + quad * 16);
    short8v sl1 = *(const short8v*)(sm + O_SL + ((wv * 2 + 1) * 16 + r15) * 144 + ks * 64 + quad * 16);
    #pragma unroll
    for (int nt = 0; nt < 2; ++nt) {
      short8v wh = *(const short8v*)(bg0 + 15360 + (nt * 16 + r15) * 144 + ks * 64 + quad * 16);
      short8v wl = *(const short8v*)(bg0 + 19968 + (nt * 16 + r15) * 144 + ks * 64 + quad * 16);
      acc[0][nt] = __builtin_amdgcn_mfma_f32_16x16x32_bf16(sh0, wh, acc[0][nt], 0, 0, 0);
      acc[0][nt] = __builtin_amdgcn_mfma_f32_16x16x32_bf16(sh0, wl, acc[0][nt], 0, 0, 0);
      acc[0][nt] = __builtin_amdgcn_mfma_f32_16x16x32_bf16(sl0, wh, acc[0][nt], 0, 0, 0);
      acc[1][nt] = __builtin_amdgcn_mfma_f32_16x16x32_bf16(sh1, wh, acc[1][nt], 0, 0, 0);
      acc[1][nt] = __builtin_amdgcn_mfma_f32_16x16x32_bf16(sh1, wl, acc[1][nt], 0, 0, 0);
      acc[1][nt] = __builtin_amdgcn_mfma_f32_16x16x32_bf16(sl1, wh, acc[1][nt], 0, 0, 0);
    }
  }
  __syncthreads();   // all S reads done; reuse S_hi base as y staging (8192 B)

  #pragma unroll
  for (int mt = 0; mt < 2; ++mt)
    #pragma unroll
    for (int nt = 0; nt < 2; ++nt)
      #pragma unroll
      for (int rg = 0; rg < 4; ++rg) {
        int c = (wv * 2 + mt) * 16 + quad * 4 + rg;
        int t = nt * 16 + r15;
        float v = gelu_exact(acc[mt][nt][rg]);
        *(unsigned short*)(sm + O_SH + (c * 32 + t) * 2) = f2bs(v);
      }
  __syncthreads();
  {
    uint4* yo = (uint4*)(y_g + (size_t)bh * L);
    #pragma unroll
    for (int r = 0; r < 2; ++r) {
      int idx = tid + r * 256;
      yo[idx] = *(const uint4*)(sm + O_SH + idx * 16);
    }
  }
}

// ------- glu_ln v13 = v11 + R4 T14 async-STAGE: tile t+1's 8 uint4 global loads are
// issued right after barrier A of tile t, so ~300-500cy load latency hides under the
// MFMA+sigmoid+LN phases instead of sitting exposed at the next tile's stage. -------
__global__ __launch_bounds__(256, 2) void glu_ln13_kernel(
    const unsigned short* __restrict__ y_g, unsigned short* __restrict__ h_g,
    const unsigned short* __restrict__ Wb,  // layer: [hi 256x128] shorts
    const float* __restrict__ ob, const float* __restrict__ lg,
    const float* __restrict__ lb, float* __restrict__ pooled) {
  static __shared__ char __align__(16) sm[36864];
  constexpr int O_Y = 0;        // y transposed [64 pos][136 ch-shorts] = 17408 B (row 272 B)
  constexpr int O_H = 17408;    // h natural [128 ch][68 pos-shorts] = 17408 B; z aliases in-place
  constexpr int O_P = 34816;    // LN partials [4 waves][64 pos] float2 = 2048 B

  int tid = threadIdx.x;
  int wv = tid >> 6, lane = tid & 63, r15 = lane & 15, quad = lane >> 4;
  int b = blockIdx.x >> 4, seg = blockIdx.x & 15;
  int yk = tid >> 1, yhalf = tid & 1;   // y staging: channel yk, 32-pos half yhalf

  float ba[2][4], bgl[2][4];
  #pragma unroll
  for (int i = 0; i < 2; ++i) {
    int ch0 = (2 * wv + i) * 16 + quad * 4;
    #pragma unroll
    for (int rg = 0; rg < 4; ++rg) {
      ba[i][rg]  = ob[ch0 + rg];
      bgl[i][rg] = ob[128 + ch0 + rg];
    }
  }
  float psum = 0.f;   // R3: fused-pool accumulator (channel tid>>1, this thread's 128 positions)

  // ---- T14 prologue: tile 0 loads into registers
  uint4 yreg[4], hreg[4];
  {
    int l0 = seg * 256;
    const uint4* src = (const uint4*)(y_g + ((size_t)(b * H + yk)) * L + l0 + yhalf * 32);
    yreg[0] = src[0]; yreg[1] = src[1]; yreg[2] = src[2]; yreg[3] = src[3];
    #pragma unroll
    for (int i = 0; i < 4; ++i) {
      int id = tid + i * 256;
      int ch = id >> 3, part = id & 7;
      hreg[i] = *(const uint4*)(h_g + ((size_t)(b * H + ch)) * L + l0 + part * 8);
    }
  }

  for (int t = 0; t < 4; ++t) {
    int l0 = seg * 256 + t * 64;
    {  // write staged regs to LDS (y transposed scalar b16; h natural uint4)
      unsigned short sarr[32];
      uint4* sp = (uint4*)sarr;
      sp[0] = yreg[0]; sp[1] = yreg[1]; sp[2] = yreg[2]; sp[3] = yreg[3];
      #pragma unroll
      for (int j = 0; j < 32; ++j)
        *(unsigned short*)(sm + O_Y + (yhalf * 32 + j) * 272 + yk * 2) = sarr[j];
      #pragma unroll
      for (int i = 0; i < 4; ++i) {
        int id = tid + i * 256;
        int ch = id >> 3, part = id & 7;
        *(uint4*)(sm + O_H + ch * 136 + part * 16) = hreg[i];
      }
    }
    __syncthreads();   // A

    if (t < 3) {   // T14: issue next tile's loads now; latency hides under compute
      int l1 = l0 + 64;
      const uint4* src = (const uint4*)(y_g + ((size_t)(b * H + yk)) * L + l1 + yhalf * 32);
      yreg[0] = src[0]; yreg[1] = src[1]; yreg[2] = src[2]; yreg[3] = src[3];
      #pragma unroll
      for (int i = 0; i < 4; ++i) {
        int id = tid + i * 256;
        int ch = id >> 3, part = id & 7;
        hreg[i] = *(const uint4*)(h_g + ((size_t)(b * H + ch)) * L + l1 + part * 8);
      }
    }

    float s1[4] = {0.f, 0.f, 0.f, 0.f}, s2[4] = {0.f, 0.f, 0.f, 0.f};
    #pragma unroll
    for (int pt = 0; pt < 4; ++pt) {
      short8v bf[4];
      #pragma unroll
      for (int ks = 0; ks < 4; ++ks)
        bf[ks] = *(const short8v*)(sm + O_Y + (pt * 16 + r15) * 272 + ks * 64 + quad * 16);
      int pos = pt * 16 + r15;
      #pragma unroll
      for (int i = 0; i < 2; ++i) {
        int ch0 = (2 * wv + i) * 16 + quad * 4;
        const unsigned short* wa = Wb + (size_t)((2 * wv + i) * 16 + r15) * 128 + quad * 8;
        floatx4 acca = (floatx4){0.f, 0.f, 0.f, 0.f};
        #pragma unroll
        for (int ks = 0; ks < 4; ++ks) {
          short8v wf = *(const short8v*)(wa + ks * 32);
          acca = __builtin_amdgcn_mfma_f32_16x16x32_bf16(wf, bf[ks], acca, 0, 0, 0);
        }
        const unsigned short* wg = Wb + (size_t)((8 + 2 * wv + i) * 16 + r15) * 128 + quad * 8;
        floatx4 accg = (floatx4){0.f, 0.f, 0.f, 0.f};
        #pragma unroll
        for (int ks = 0; ks < 4; ++ks) {
          short8v wf = *(const short8v*)(wg + ks * 32);
          accg = __builtin_amdgcn_mfma_f32_16x16x32_bf16(wf, bf[ks], accg, 0, 0, 0);
        }
        #pragma unroll
        for (int rg = 0; rg < 4; ++rg) {
          float a = acca[rg] + ba[i][rg];
          float g = accg[rg] + bgl[i][rg];
          float eg = __builtin_amdgcn_exp2f(g * -1.4426950408889634f);
          float zz = a * __builtin_amdgcn_rcpf(1.f + eg);
          char* slot = sm + O_H + (ch0 + rg) * 136 + pos * 2;
          zz += bu2f(*(const unsigned short*)slot);   // residual read
          s1[pt] += zz;
          s2[pt] += zz * zz;
          *(unsigned short*)slot = f2bs(zz);          // z write, same slot, same lane
        }
      }
    }
    #pragma unroll
    for (int pt = 0; pt < 4; ++pt) {
      s1[pt] += __shfl_xor(s1[pt], 16, 64); s1[pt] += __shfl_xor(s1[pt], 32, 64);
      s2[pt] += __shfl_xor(s2[pt], 16, 64); s2[pt] += __shfl_xor(s2[pt], 32, 64);
    }
    if (quad == 0) {
      #pragma unroll
      for (int pt = 0; pt < 4; ++pt)
        *(float2*)(sm + O_P + (wv * 64 + pt * 16 + r15) * 8) = make_float2(s1[pt], s2[pt]);
    }
    __syncthreads();   // B

    if (tid < 64) {
      float a1 = 0.f, a2 = 0.f;
      #pragma unroll
      for (int w = 0; w < 4; ++w) {
        float2 p = *(const float2*)(sm + O_P + (w * 64 + tid) * 8);
        a1 += p.x; a2 += p.y;
      }
      float m = a1 * (1.f / H);
      float var = a2 * (1.f / H) - m * m;
      if (var < 0.f) var = 0.f;
      *(float2*)(sm + O_P + tid * 8) = make_float2(m, rsqrtf(var + 1e-5f));
    }
    __syncthreads();   // C

    {
      int ch = tid >> 1, half = tid & 1;
      float gg = lg[ch], bb2 = lb[ch];
      unsigned outw[16];
      #pragma unroll
      for (int j = 0; j < 16; ++j) {
        int p0 = half * 32 + 2 * j;
        float z0 = bu2f(*(const unsigned short*)(sm + O_H + ch * 136 + p0 * 2));
        float z1 = bu2f(*(const unsigned short*)(sm + O_H + ch * 136 + p0 * 2 + 2));
        float2 m0 = *(const float2*)(sm + O_P + p0 * 8);
        float2 m1 = *(const float2*)(sm + O_P + (p0 + 1) * 8);
        float o0 = (z0 - m0.x) * m0.y * gg + bb2;
        float o1 = (z1 - m1.x) * m1.y * gg + bb2;
        psum += o0 + o1;
        outw[j] = pack2(o0, o1);
      }
      uint4* dst = (uint4*)(h_g + ((size_t)(b * H + ch)) * L + l0 + half * 32);
      #pragma unroll
      for (int j = 0; j < 4; ++j)
        dst[j] = *(const uint4*)(&outw[j * 4]);
    }
    __syncthreads();   // D
  }

  if (pooled != nullptr) {   // final layer only: fused mean-pool partials
    psum += __shfl_xor(psum, 1, 64);          // combine the two halves of this channel
    if ((tid & 1) == 0)
      atomicAdd(pooled + b * H + (tid >> 1), psum);
  }
}

__global__ void head_kernel(const float* __restrict__ pooled,
                            const float* __restrict__ head_W,
                            const float* __restrict__ head_b,
                            float* __restrict__ out) {
  int tid = threadIdx.x;
  if (tid >= B * 2) return;
  int b = tid >> 1, o = tid & 1;
  float acc = 0.f;
  for (int ch = 0; ch < H; ++ch)
    acc += pooled[b * H + ch] * head_W[ch * 2 + o];
  out[tid] = head_b[o] + acc * (1.f / L);   // pooled holds SUM over L (fused pool)
}

extern "C" void kernel_launch(void* const* d_in, const int* in_sizes, int n_in,
                              void* d_out, int out_size, void* d_ws, size_t ws_size,
                              hipStream_t stream) {
  const float* x          = (const float*)d_in[0];
  const float* enc_W      = (const float*)d_in[1];
  const float* enc_b      = (const float*)d_in[2];
  const float* log_dt     = (const float*)d_in[3];
  const float* C_re       = (const float*)d_in[4];
  const float* C_im       = (const float*)d_in[5];
  const float* log_A_real = (const float*)d_in[6];
  const float* A_imag     = (const float*)d_in[7];
  const float* Dp         = (const float*)d_in[8];
  const float* out_W      = (const float*)d_in[9];
  const float* out_b      = (const float*)d_in[10];
  const float* ln_g       = (const float*)d_in[11];
  const float* ln_b       = (const float*)d_in[12];
  const float* head_W     = (const float*)d_in[13];
  const float* head_b     = (const float*)d_in[14];

  // ws (~84.6 MB): hbuf bf16 32MB | ybuf bf16 32MB | Wb 1.5MB | pooled 16KB |
  //                Bg (all layers) 18.9MB | wTg (all layers) 196KB
  bf16* hbuf = (bf16*)d_ws;
  bf16* ybuf = hbuf + (size_t)B * H * L;
  unsigned short* Wb = (unsigned short*)(ybuf + (size_t)B * H * L);
  float* pooled = (float*)(Wb + (size_t)NL * 65536);
  unsigned short* Bg = (unsigned short*)(pooled + B * H);
  float2* wTg = (float2*)(Bg + (size_t)NL * H * 12288);

  encoder_kernel<<<B * H, 256, 0, stream>>>(x, enc_W, enc_b, hbuf, pooled);
  w_prep_kernel<<<(NL * 2 * H * H + 255) / 256, 256, 0, stream>>>(out_W, Wb);
  s4d_prep_all_kernel<<<NL * H, 256, 0, stream>>>(log_dt, C_re, C_im, log_A_real,
                                                  A_imag, Dp, Bg, wTg);

  for (int layer = 0; layer < NL; ++layer) {
    s4d_conv7_kernel<<<B * H, 256, 0, stream>>>(
        hbuf, ybuf, Bg + (size_t)layer * H * 12288, wTg + (size_t)layer * H * NC);
    glu_ln13_kernel<<<B * 16, 256, 0, stream>>>(
        (const unsigned short*)ybuf, (unsigned short*)hbuf,
        Wb + (size_t)layer * 65536, out_b + layer * 2 * H,
        ln_g + layer * H, ln_b + layer * H,
        (layer == NL - 1) ? pooled : nullptr);
  }

  head_kernel<<<1, 64, 0, stream>>>(pooled, head_W, head_b, (float*)d_out);
}

// Round 7
// 468.597 us; speedup vs baseline: 1.1066x; 1.1066x over previous
//
#include <hip/hip_runtime.h>
#include <hip/hip_bf16.h>

#define B 32
#define H 128
#define L 4096
#define NC 32
#define NL 6
#define NCHUNK 128

typedef __hip_bfloat16 bf16;
typedef __attribute__((ext_vector_type(8))) short short8v;   // 8 bf16 (4 VGPR)
typedef __attribute__((ext_vector_type(4))) float floatx4;   // MFMA C/D

__device__ __forceinline__ float b2f(bf16 v) { return __bfloat162float(v); }
__device__ __forceinline__ float bu2f(unsigned int u) {
  union { unsigned int i; float f; } v; v.i = u << 16; return v.f;
}
// float -> bf16 bits via HW RNE convert
__device__ __forceinline__ unsigned short f2bs(float f) {
  bf16 b = __float2bfloat16(f);
  union { bf16 h; unsigned short s; } cv; cv.h = b; return cv.s;
}
// two floats -> packed bf16 dword (a low, b high) via v_cvt_pk_bf16_f32
__device__ __forceinline__ unsigned pack2(float a, float b) {
  union { __hip_bfloat162 h; unsigned u; } cv;
  cv.h = __float22bfloat162_rn(make_float2(a, b));
  return cv.u;
}

// Branch-free exact GELU: erf via Abramowitz-Stegun 7.1.26 (|eps|<=1.5e-7),
// v_rcp + v_exp instead of libm erff's divergent two-path rational (~50 slot-ops -> ~14).
__device__ __forceinline__ float gelu_exact(float v) {
  float ax = fabsf(v) * 0.70710678118654752f;                 // |v|/sqrt(2)
  float t  = __builtin_amdgcn_rcpf(fmaf(0.3275911f, ax, 1.f));
  float p  = t * fmaf(t, fmaf(t, fmaf(t, fmaf(t, 1.061405429f, -1.453152027f),
                                      1.421413741f), -0.284496736f), 0.254829592f);
  float e  = __builtin_amdgcn_exp2f(ax * ax * -1.4426950408889634f);  // exp(-x^2)
  float er = fmaf(-p, e, 1.f);                                // erf(|x|)
  return v * fmaf(0.5f, copysignf(er, v), 0.5f);              // v*0.5*(1+erf(v/sqrt2))
}

// ---------------- R5 fused front-end: encoder + s4d_prep + w_prep in ONE dispatch.
// The three are mutually independent; merging removes 2 launch gaps and lets the
// latency-bound prep overlap the write-bound encoder. Blocks branch uniformly:
//   [0, B*H)                encoder (R2 vectorized; R3 pooled zero-init)
//   [B*H, B*H+NL*H)         s4d_prep (R1 power-table version)
//   [B*H+NL*H, +768)        w_prep
__global__ __launch_bounds__(256) void fused_prep_kernel(
    const float* __restrict__ x, const float* __restrict__ enc_W,
    const float* __restrict__ enc_b, bf16* __restrict__ h, float* __restrict__ pooled,
    const float* __restrict__ out_W, unsigned short* __restrict__ Wb,
    const float* __restrict__ log_dt, const float* __restrict__ C_re,
    const float* __restrict__ C_im, const float* __restrict__ log_A_real,
    const float* __restrict__ A_imag, const float* __restrict__ Dp,
    unsigned short* __restrict__ Bg, float2* __restrict__ wTg) {
  __shared__ float2 cd_s[NC];
  __shared__ float K_s[32];
  __shared__ float2 P_s[NC][33];   // w_n^k, k=0..32
  int blk = blockIdx.x;
  int tid = threadIdx.x;

  if (blk < B * H) {   // ---------------- encoder ----------------
    int b = blk >> 7, ch = blk & 127;
    if (tid == 0) pooled[blk] = 0.f;   // (b*H+ch) == blk
    float w0 = enc_W[ch];
    float w1 = enc_W[H + ch];
    float bb = enc_b[ch];
    const float4* x0 = (const float4*)(x + (size_t)b * 2 * L);
    const float4* x1 = (const float4*)(x + (size_t)b * 2 * L + L);
    uint4* out = (uint4*)(h + ((size_t)b * H + ch) * L);
    for (int i = tid; i < L / 8; i += blockDim.x) {
      float4 a0 = x0[2 * i], a1 = x0[2 * i + 1];
      float4 c0 = x1[2 * i], c1 = x1[2 * i + 1];
      unsigned q0 = pack2(fmaf(a0.x, w0, fmaf(c0.x, w1, bb)), fmaf(a0.y, w0, fmaf(c0.y, w1, bb)));
      unsigned q1 = pack2(fmaf(a0.z, w0, fmaf(c0.z, w1, bb)), fmaf(a0.w, w0, fmaf(c0.w, w1, bb)));
      unsigned q2 = pack2(fmaf(a1.x, w0, fmaf(c1.x, w1, bb)), fmaf(a1.y, w0, fmaf(c1.y, w1, bb)));
      unsigned q3 = pack2(fmaf(a1.z, w0, fmaf(c1.z, w1, bb)), fmaf(a1.w, w0, fmaf(c1.w, w1, bb)));
      out[i] = make_uint4(q0, q1, q2, q3);
    }
    return;
  }

  if (blk >= B * H + NL * H) {   // ---------------- w_prep ----------------
    int idx = (blk - (B * H + NL * H)) * 256 + tid;
    if (idx >= NL * 2 * H * H) return;
    int l = idx / (2 * H * H);
    int rem = idx % (2 * H * H);
    float v = out_W[idx];
    unsigned short hi = f2bs(v);
    unsigned short lo = f2bs(v - bu2f(hi));
    Wb[(size_t)l * 65536 + rem] = hi;
    Wb[(size_t)l * 65536 + 32768 + rem] = lo;
    return;
  }

  // ---------------- s4d_prep (R1: power table, zero transcendentals in bulk) ----
  int lh = blk - B * H;
  int layer = lh >> 7, hh = lh & 127;
  if (tid < NC) {
    int n = tid, base = (layer * H + hh) * NC + n;
    float dt = expf(log_dt[layer * H + hh]);
    float Are = -expf(log_A_real[base]);
    float Aim = A_imag[base];
    float dre = dt * Are, dim = dt * Aim;
    float er = expf(dre);
    float wre = er * cosf(dim), wim = er * sinf(dim);
    float emre = wre - 1.f, emim = wim;   // expm1(dtA)
    float cre = C_re[base], cim = C_im[base];
    float nre = cre * emre - cim * emim, nim = cre * emim + cim * emre;
    float den = Are * Are + Aim * Aim;
    cd_s[n] = make_float2((nre * Are + nim * Aim) / den, (nim * Are - nre * Aim) / den);
    float e32 = expf(dre * 32.f);
    wTg[lh * NC + n] = make_float2(e32 * cosf(dim * 32.f), e32 * sinf(dim * 32.f));
    // power walk: P[n][k] = w^k (sequential cmul; |w|<1 so error doesn't amplify)
    P_s[n][0] = make_float2(1.f, 0.f);
    P_s[n][1] = make_float2(wre, wim);
    float rr = wre, ri = wim;
    #pragma unroll
    for (int k = 2; k <= 32; ++k) {
      float nr = rr * wre - ri * wim;
      ri = rr * wim + ri * wre;
      rr = nr;
      P_s[n][k] = make_float2(rr, ri);
    }
  }
  __syncthreads();
  if (tid < 32) {  // K[tau] = 2 sum_n Re(cd_n w_n^tau)
    float acc = 0.f;
    for (int n = 0; n < NC; ++n) {
      float2 p = P_s[n][tid];
      acc += cd_s[n].x * p.x - cd_s[n].y * p.y;
    }
    K_s[tid] = 2.f * acc;
  }
  __syncthreads();
  unsigned short* bb = Bg + (size_t)lh * 12288;
  float Dv = Dp[layer * H + hh];
  #pragma unroll
  for (int i = 0; i < 8; ++i) {     // VT: 2048 entries = Re/Im w^(31-t)
    int idx = tid + i * 256;
    int n2 = idx >> 5, t = idx & 31, n = n2 >> 1;
    float2 p = P_s[n][31 - t];
    float v = (n2 & 1) ? p.y : p.x;
    unsigned short hi = f2bs(v);
    unsigned short lo = f2bs(v - bu2f(hi));
    bb[n2 * 40 + t] = hi;
    bb[2560 + n2 * 40 + t] = lo;
  }
  #pragma unroll
  for (int i = 0; i < 4; ++i) {     // KT: 1024 entries
    int idx = tid + i * 256;
    int t = idx >> 5, m = idx & 31;
    float v = (m > t) ? 0.f : (K_s[t - m] + (m == t ? Dv : 0.f));
    unsigned short hi = f2bs(v);
    unsigned short lo = f2bs(v - bu2f(hi));
    bb[5120 + t * 40 + m] = hi;
    bb[6400 + t * 40 + m] = lo;
  }
  #pragma unroll
  for (int i = 0; i < 8; ++i) {     // WT: 2048 entries = ±2·{Re,Im}(cd_n w^(t+1))
    int idx = tid + i * 256;
    int t = idx >> 6, k = idx & 63, n = k >> 1;
    float2 p = P_s[n][t + 1];
    float cwr = cd_s[n].x * p.x - cd_s[n].y * p.y;
    float cwi = cd_s[n].x * p.y + cd_s[n].y * p.x;
    float v = (k & 1) ? -2.f * cwi : 2.f * cwr;
    unsigned short hi = f2bs(v);
    unsigned short lo = f2bs(v - bu2f(hi));
    bb[7680 + t * 72 + k] = hi;
    bb[9984 + t * 72 + k] = lo;
  }
}

// ---------------- S4D conv v7: no U staging (A-frags direct from global), GT/GE in
// S-row pads; LDS 37120 B -> 4 blocks/CU. Epilogue stages y through dead S_hi.
// R0: GELU via branch-free A&S erf (was libm erff — dominant VALU cost). ----------
__global__ __launch_bounds__(256, 4) void s4d_conv7_kernel(
    const bf16* __restrict__ u_g, bf16* __restrict__ y_g,
    const unsigned short* __restrict__ Bg, const float2* __restrict__ wTg) {
  static __shared__ char __align__(16) sm[37120];
  constexpr int O_SH = 0;       // scan re / packed hi: 128 rows x 144 B (cols 0..127 + 16 B pad)
  constexpr int O_SL = 18432;   // scan im / packed lo
  constexpr int O_WT = 36864;   // wT [32] float2 = 256 B
  // GT[i] lives in S_hi pad: O_SH + (i>>1)*144 + 128 + (i&1)*8   (i = g*32+n)
  // GE[i] lives in S_lo pad: O_SL + (i>>1)*144 + 128 + (i&1)*8

  int tid = threadIdx.x;
  int lane = tid & 63, wv = tid >> 6;
  int r15 = lane & 15, quad = lane >> 4;
  int bh = blockIdx.x, hh = bh & 127;
  const char* bg0 = (const char*)(Bg + (size_t)hh * 12288);
  const char* ug0 = (const char*)(u_g + (size_t)bh * L);

  if (tid < 32) *(float2*)(sm + O_WT + tid * 8) = wTg[hh * 32 + tid];

  // A-fragments direct from global (fully coalesced 16 B/lane within a 4 KB span)
  short8v aU0 = *(const short8v*)(ug0 + ((wv * 2 + 0) * 16 + r15) * 64 + quad * 16);
  short8v aU1 = *(const short8v*)(ug0 + ((wv * 2 + 1) * 16 + r15) * 64 + quad * 16);
  // V fragments from L2
  short8v bvh[4], bvl[4];
  #pragma unroll
  for (int nt = 0; nt < 4; ++nt) {
    bvh[nt] = *(const short8v*)(bg0 + 0    + (nt * 16 + r15) * 80 + quad * 16);
    bvl[nt] = *(const short8v*)(bg0 + 5120 + (nt * 16 + r15) * 80 + quad * 16);
  }

  // ---- phase P (no barrier needed before: all inputs are regs)
  floatx4 cp[2][4];
  #pragma unroll
  for (int mt = 0; mt < 2; ++mt)
    #pragma unroll
    for (int nt = 0; nt < 4; ++nt) cp[mt][nt] = (floatx4){0.f, 0.f, 0.f, 0.f};
  #pragma unroll
  for (int nt = 0; nt < 4; ++nt) {
    cp[0][nt] = __builtin_amdgcn_mfma_f32_16x16x32_bf16(aU0, bvh[nt], cp[0][nt], 0, 0, 0);
    cp[0][nt] = __builtin_amdgcn_mfma_f32_16x16x32_bf16(aU0, bvl[nt], cp[0][nt], 0, 0, 0);
    cp[1][nt] = __builtin_amdgcn_mfma_f32_16x16x32_bf16(aU1, bvh[nt], cp[1][nt], 0, 0, 0);
    cp[1][nt] = __builtin_amdgcn_mfma_f32_16x16x32_bf16(aU1, bvl[nt], cp[1][nt], 0, 0, 0);
  }
  #pragma unroll
  for (int mt = 0; mt < 2; ++mt)
    #pragma unroll
    for (int nt = 0; nt < 4; ++nt) {
      int n2 = nt * 16 + r15;
      int off = ((n2 & 1) ? O_SL : O_SH) + (n2 >> 1) * 4;
      #pragma unroll
      for (int rg = 0; rg < 4; ++rg) {
        int c = (wv * 2 + mt) * 16 + quad * 4 + rg;
        *(float*)(sm + off + c * 144) = cp[mt][nt][rg];
      }
    }
  __syncthreads();   // P stores + wT visible

  // ---- scan A: batched loads, recurrence in regs, prefixes HELD in regs
  int sg = tid >> 5, sn = tid & 31;
  float2 swt = *(const float2*)(sm + O_WT + sn * 8);
  float epr[16], epi[16];
  {
    float pr_[16], pi_[16];
    #pragma unroll
    for (int k = 0; k < 16; ++k) {
      pr_[k] = *(const float*)(sm + O_SH + (sg * 16 + k) * 144 + sn * 4);
      pi_[k] = *(const float*)(sm + O_SL + (sg * 16 + k) * 144 + sn * 4);
    }
    float rr = 0.f, ri = 0.f;
    #pragma unroll
    for (int k = 0; k < 16; ++k) {
      epr[k] = rr; epi[k] = ri;
      float nr = swt.x * rr - swt.y * ri + pr_[k];
      ri = swt.x * ri + swt.y * rr + pi_[k];
      rr = nr;
    }
    int i = sg * 32 + sn;
    *(float2*)(sm + O_SH + (i >> 1) * 144 + 128 + (i & 1) * 8) = make_float2(rr, ri);  // GT
  }
  __syncthreads();
  // ---- scan B: serial over 8 groups; wT^16 via 4 squarings
  if (tid < 32) {
    float2 wt = *(const float2*)(sm + O_WT + tid * 8);
    float w2r = wt.x * wt.x - wt.y * wt.y,   w2i = 2.f * wt.x * wt.y;
    float w4r = w2r * w2r - w2i * w2i,       w4i = 2.f * w2r * w2i;
    float w8r = w4r * w4r - w4i * w4i,       w8i = 2.f * w4r * w4i;
    float w16r = w8r * w8r - w8i * w8i,      w16i = 2.f * w8r * w8i;
    float rr = 0.f, ri = 0.f;
    for (int g = 0; g < 8; ++g) {
      int i = g * 32 + tid;
      *(float2*)(sm + O_SL + (i >> 1) * 144 + 128 + (i & 1) * 8) = make_float2(rr, ri);  // GE
      float2 gt = *(const float2*)(sm + O_SH + (i >> 1) * 144 + 128 + (i & 1) * 8);
      float nr = w16r * rr - w16i * ri + gt.x;
      ri = w16r * ri + w16i * rr + gt.y;
      rr = nr;
    }
  }
  __syncthreads();
  // ---- fixup: E[c] = prefix + wT^k * GE[g]; HW packed-cvt hi/lo write
  {
    int i = sg * 32 + sn;
    float2 ge = *(const float2*)(sm + O_SL + (i >> 1) * 144 + 128 + (i & 1) * 8);
    float ar = ge.x, ai = ge.y;   // wT^0 * GE
    #pragma unroll
    for (int k = 0; k < 16; ++k) {
      int c = sg * 16 + k;
      float er = epr[k] + ar;
      float ei = epi[k] + ai;
      unsigned uh = pack2(er, ei);
      *(unsigned*)(sm + O_SH + c * 144 + sn * 4) = uh;
      *(unsigned*)(sm + O_SL + c * 144 + sn * 4) =
          pack2(er - bu2f(uh & 0xffffu), ei - bu2f(uh >> 16));
      float nr = ar * swt.x - ai * swt.y;   // advance wT^k * GE
      ai = ar * swt.y + ai * swt.x;
      ar = nr;
    }
  }
  __syncthreads();

  // ---- Toeplitz + modal MFMAs (K/W frags direct from L2)
  floatx4 acc[2][2];
  #pragma unroll
  for (int mt = 0; mt < 2; ++mt)
    #pragma unroll
    for (int nt = 0; nt < 2; ++nt) acc[mt][nt] = (floatx4){0.f, 0.f, 0.f, 0.f};
  #pragma unroll
  for (int nt = 0; nt < 2; ++nt) {
    short8v kh = *(const short8v*)(bg0 + 10240 + (nt * 16 + r15) * 80 + quad * 16);
    short8v kl = *(const short8v*)(bg0 + 12800 + (nt * 16 + r15) * 80 + quad * 16);
    acc[0][nt] = __builtin_amdgcn_mfma_f32_16x16x32_bf16(aU0, kh, acc[0][nt], 0, 0, 0);
    acc[0][nt] = __builtin_amdgcn_mfma_f32_16x16x32_bf16(aU0, kl, acc[0][nt], 0, 0, 0);
    acc[1][nt] = __builtin_amdgcn_mfma_f32_16x16x32_bf16(aU1, kh, acc[1][nt], 0, 0, 0);
    acc[1][nt] = __builtin_amdgcn_mfma_f32_16x16x32_bf16(aU1, kl, acc[1][nt], 0, 0, 0);
  }
  #pragma unroll
  for (int ks = 0; ks < 2; ++ks) {
    short8v sh0 = *(const short8v*)(sm + O_SH + ((wv * 2 + 0) * 16 + r15) * 144 + ks * 64 + quad * 16);
    short8v sh1 = *(const short8v*)(sm + O_SH + ((wv * 2 + 1) * 16 + r15) * 144 + ks * 64 + quad * 16);
    short8v sl0 = *(const short8v*)(sm + O_SL + ((wv * 2 + 0) * 16 + r15) * 144 + ks * 64 + quad * 16);
    short8v sl1 = *(const short8v*)(sm + O_SL + ((wv * 2 + 1) * 16 + r15) * 144 + ks * 64 + quad * 16);
    #pragma unroll
    for (int nt = 0; nt < 2; ++nt) {
      short8v wh = *(const short8v*)(bg0 + 15360 + (nt * 16 + r15) * 144 + ks * 64 + quad * 16);
      short8v wl = *(const short8v*)(bg0 + 19968 + (nt * 16 + r15) * 144 + ks * 64 + quad * 16);
      acc[0][nt] = __builtin_amdgcn_mfma_f32_16x16x32_bf16(sh0, wh, acc[0][nt], 0, 0, 0);
      acc[0][nt] = __builtin_amdgcn_mfma_f32_16x16x32_bf16(sh0, wl, acc[0][nt], 0, 0, 0);
      acc[0][nt] = __builtin_amdgcn_mfma_f32_16x16x32_bf16(sl0, wh, acc[0][nt], 0, 0, 0);
      acc[1][nt] = __builtin_amdgcn_mfma_f32_16x16x32_bf16(sh1, wh, acc[1][nt], 0, 0, 0);
      acc[1][nt] = __builtin_amdgcn_mfma_f32_16x16x32_bf16(sh1, wl, acc[1][nt], 0, 0, 0);
      acc[1][nt] = __builtin_amdgcn_mfma_f32_16x16x32_bf16(sl1, wh, acc[1][nt], 0, 0, 0);
    }
  }
  __syncthreads();   // all S reads done; reuse S_hi base as y staging (8192 B)

  #pragma unroll
  for (int mt = 0; mt < 2; ++mt)
    #pragma unroll
    for (int nt = 0; nt < 2; ++nt)
      #pragma unroll
      for (int rg = 0; rg < 4; ++rg) {
        int c = (wv * 2 + mt) * 16 + quad * 4 + rg;
        int t = nt * 16 + r15;
        float v = gelu_exact(acc[mt][nt][rg]);
        *(unsigned short*)(sm + O_SH + (c * 32 + t) * 2) = f2bs(v);
      }
  __syncthreads();
  {
    uint4* yo = (uint4*)(y_g + (size_t)bh * L);
    #pragma unroll
    for (int r = 0; r < 2; ++r) {
      int idx = tid + r * 256;
      yo[idx] = *(const uint4*)(sm + O_SH + idx * 16);
    }
  }
}

// ------- glu_ln v11 (proven; R5: reverted R4's T14 prefetch — it raised VGPR 60->120
// and HBM traffic 67->104 MB, costing +10 us/dispatch. v11's in-loop stage is the
// empirically best schedule at this grid (2 blocks/CU, grid-limited). -------
__global__ __launch_bounds__(256, 2) void glu_ln11_kernel(
    const unsigned short* __restrict__ y_g, unsigned short* __restrict__ h_g,
    const unsigned short* __restrict__ Wb,  // layer: [hi 256x128] shorts
    const float* __restrict__ ob, const float* __restrict__ lg,
    const float* __restrict__ lb, float* __restrict__ pooled) {
  static __shared__ char __align__(16) sm[36864];
  constexpr int O_Y = 0;        // y transposed [64 pos][136 ch-shorts] = 17408 B (row 272 B)
  constexpr int O_H = 17408;    // h natural [128 ch][68 pos-shorts] = 17408 B; z aliases in-place
  constexpr int O_P = 34816;    // LN partials [4 waves][64 pos] float2 = 2048 B

  int tid = threadIdx.x;
  int wv = tid >> 6, lane = tid & 63, r15 = lane & 15, quad = lane >> 4;
  int b = blockIdx.x >> 4, seg = blockIdx.x & 15;

  float ba[2][4], bgl[2][4];
  #pragma unroll
  for (int i = 0; i < 2; ++i) {
    int ch0 = (2 * wv + i) * 16 + quad * 4;
    #pragma unroll
    for (int rg = 0; rg < 4; ++rg) {
      ba[i][rg]  = ob[ch0 + rg];
      bgl[i][rg] = ob[128 + ch0 + rg];
    }
  }
  float psum = 0.f;   // R3: fused-pool accumulator (channel tid>>1, this thread's 128 positions)

  for (int t = 0; t < 4; ++t) {
    int l0 = seg * 256 + t * 64;
    {
      int k = tid >> 1, half = tid & 1;
      const uint4* src = (const uint4*)(y_g + ((size_t)(b * H + k)) * L + l0 + half * 32);
      unsigned short sarr[32];
      uint4* sp = (uint4*)sarr;
      sp[0] = src[0]; sp[1] = src[1]; sp[2] = src[2]; sp[3] = src[3];
      #pragma unroll
      for (int j = 0; j < 32; ++j)
        *(unsigned short*)(sm + O_Y + (half * 32 + j) * 272 + k * 2) = sarr[j];
    }
    {
      #pragma unroll
      for (int i = 0; i < 4; ++i) {
        int id = tid + i * 256;           // 0..1023
        int ch = id >> 3, part = id & 7;
        uint4 v = *(const uint4*)(h_g + ((size_t)(b * H + ch)) * L + l0 + part * 8);
        *(uint4*)(sm + O_H + ch * 136 + part * 16) = v;
      }
    }
    __syncthreads();   // A

    float s1[4] = {0.f, 0.f, 0.f, 0.f}, s2[4] = {0.f, 0.f, 0.f, 0.f};
    #pragma unroll
    for (int pt = 0; pt < 4; ++pt) {
      short8v bf[4];
      #pragma unroll
      for (int ks = 0; ks < 4; ++ks)
        bf[ks] = *(const short8v*)(sm + O_Y + (pt * 16 + r15) * 272 + ks * 64 + quad * 16);
      int pos = pt * 16 + r15;
      #pragma unroll
      for (int i = 0; i < 2; ++i) {
        int ch0 = (2 * wv + i) * 16 + quad * 4;
        const unsigned short* wa = Wb + (size_t)((2 * wv + i) * 16 + r15) * 128 + quad * 8;
        floatx4 acca = (floatx4){0.f, 0.f, 0.f, 0.f};
        #pragma unroll
        for (int ks = 0; ks < 4; ++ks) {
          short8v wf = *(const short8v*)(wa + ks * 32);
          acca = __builtin_amdgcn_mfma_f32_16x16x32_bf16(wf, bf[ks], acca, 0, 0, 0);
        }
        const unsigned short* wg = Wb + (size_t)((8 + 2 * wv + i) * 16 + r15) * 128 + quad * 8;
        floatx4 accg = (floatx4){0.f, 0.f, 0.f, 0.f};
        #pragma unroll
        for (int ks = 0; ks < 4; ++ks) {
          short8v wf = *(const short8v*)(wg + ks * 32);
          accg = __builtin_amdgcn_mfma_f32_16x16x32_bf16(wf, bf[ks], accg, 0, 0, 0);
        }
        #pragma unroll
        for (int rg = 0; rg < 4; ++rg) {
          float a = acca[rg] + ba[i][rg];
          float g = accg[rg] + bgl[i][rg];
          float eg = __builtin_amdgcn_exp2f(g * -1.4426950408889634f);
          float zz = a * __builtin_amdgcn_rcpf(1.f + eg);
          char* slot = sm + O_H + (ch0 + rg) * 136 + pos * 2;
          zz += bu2f(*(const unsigned short*)slot);   // residual read
          s1[pt] += zz;
          s2[pt] += zz * zz;
          *(unsigned short*)slot = f2bs(zz);          // z write, same slot, same lane
        }
      }
    }
    #pragma unroll
    for (int pt = 0; pt < 4; ++pt) {
      s1[pt] += __shfl_xor(s1[pt], 16, 64); s1[pt] += __shfl_xor(s1[pt], 32, 64);
      s2[pt] += __shfl_xor(s2[pt], 16, 64); s2[pt] += __shfl_xor(s2[pt], 32, 64);
    }
    if (quad == 0) {
      #pragma unroll
      for (int pt = 0; pt < 4; ++pt)
        *(float2*)(sm + O_P + (wv * 64 + pt * 16 + r15) * 8) = make_float2(s1[pt], s2[pt]);
    }
    __syncthreads();   // B

    if (tid < 64) {
      float a1 = 0.f, a2 = 0.f;
      #pragma unroll
      for (int w = 0; w < 4; ++w) {
        float2 p = *(const float2*)(sm + O_P + (w * 64 + tid) * 8);
        a1 += p.x; a2 += p.y;
      }
      float m = a1 * (1.f / H);
      float var = a2 * (1.f / H) - m * m;
      if (var < 0.f) var = 0.f;
      *(float2*)(sm + O_P + tid * 8) = make_float2(m, rsqrtf(var + 1e-5f));
    }
    __syncthreads();   // C

    {
      int ch = tid >> 1, half = tid & 1;
      float gg = lg[ch], bb2 = lb[ch];
      unsigned outw[16];
      #pragma unroll
      for (int j = 0; j < 16; ++j) {
        int p0 = half * 32 + 2 * j;
        float z0 = bu2f(*(const unsigned short*)(sm + O_H + ch * 136 + p0 * 2));
        float z1 = bu2f(*(const unsigned short*)(sm + O_H + ch * 136 + p0 * 2 + 2));
        float2 m0 = *(const float2*)(sm + O_P + p0 * 8);
        float2 m1 = *(const float2*)(sm + O_P + (p0 + 1) * 8);
        float o0 = (z0 - m0.x) * m0.y * gg + bb2;
        float o1 = (z1 - m1.x) * m1.y * gg + bb2;
        psum += o0 + o1;
        outw[j] = pack2(o0, o1);
      }
      uint4* dst = (uint4*)(h_g + ((size_t)(b * H + ch)) * L + l0 + half * 32);
      #pragma unroll
      for (int j = 0; j < 4; ++j)
        dst[j] = *(const uint4*)(&outw[j * 4]);
    }
    __syncthreads();   // D
  }

  if (pooled != nullptr) {   // final layer only: fused mean-pool partials
    psum += __shfl_xor(psum, 1, 64);          // combine the two halves of this channel
    if ((tid & 1) == 0)
      atomicAdd(pooled + b * H + (tid >> 1), psum);
  }
}

__global__ void head_kernel(const float* __restrict__ pooled,
                            const float* __restrict__ head_W,
                            const float* __restrict__ head_b,
                            float* __restrict__ out) {
  int tid = threadIdx.x;
  if (tid >= B * 2) return;
  int b = tid >> 1, o = tid & 1;
  float acc = 0.f;
  for (int ch = 0; ch < H; ++ch)
    acc += pooled[b * H + ch] * head_W[ch * 2 + o];
  out[tid] = head_b[o] + acc * (1.f / L);   // pooled holds SUM over L (fused pool)
}

extern "C" void kernel_launch(void* const* d_in, const int* in_sizes, int n_in,
                              void* d_out, int out_size, void* d_ws, size_t ws_size,
                              hipStream_t stream) {
  const float* x          = (const float*)d_in[0];
  const float* enc_W      = (const float*)d_in[1];
  const float* enc_b      = (const float*)d_in[2];
  const float* log_dt     = (const float*)d_in[3];
  const float* C_re       = (const float*)d_in[4];
  const float* C_im       = (const float*)d_in[5];
  const float* log_A_real = (const float*)d_in[6];
  const float* A_imag     = (const float*)d_in[7];
  const float* Dp         = (const float*)d_in[8];
  const float* out_W      = (const float*)d_in[9];
  const float* out_b      = (const float*)d_in[10];
  const float* ln_g       = (const float*)d_in[11];
  const float* ln_b       = (const float*)d_in[12];
  const float* head_W     = (const float*)d_in[13];
  const float* head_b     = (const float*)d_in[14];

  // ws (~84.6 MB): hbuf bf16 32MB | ybuf bf16 32MB | Wb 1.5MB | pooled 16KB |
  //                Bg (all layers) 18.9MB | wTg (all layers) 196KB
  bf16* hbuf = (bf16*)d_ws;
  bf16* ybuf = hbuf + (size_t)B * H * L;
  unsigned short* Wb = (unsigned short*)(ybuf + (size_t)B * H * L);
  float* pooled = (float*)(Wb + (size_t)NL * 65536);
  unsigned short* Bg = (unsigned short*)(pooled + B * H);
  float2* wTg = (float2*)(Bg + (size_t)NL * H * 12288);

  // R5: one fused front-end dispatch (encoder + s4d_prep + w_prep)
  int nwp = (NL * 2 * H * H + 255) / 256;
  fused_prep_kernel<<<B * H + NL * H + nwp, 256, 0, stream>>>(
      x, enc_W, enc_b, hbuf, pooled, out_W, Wb,
      log_dt, C_re, C_im, log_A_real, A_imag, Dp, Bg, wTg);

  for (int layer = 0; layer < NL; ++layer) {
    s4d_conv7_kernel<<<B * H, 256, 0, stream>>>(
        hbuf, ybuf, Bg + (size_t)layer * H * 12288, wTg + (size_t)layer * H * NC);
    glu_ln11_kernel<<<B * 16, 256, 0, stream>>>(
        (const unsigned short*)ybuf, (unsigned short*)hbuf,
        Wb + (size_t)layer * 65536, out_b + layer * 2 * H,
        ln_g + layer * H, ln_b + layer * H,
        (layer == NL - 1) ? pooled : nullptr);
  }

  head_kernel<<<1, 64, 0, stream>>>(pooled, head_W, head_b, (float*)d_out);
}

// Round 8
// 460.925 us; speedup vs baseline: 1.1250x; 1.0166x over previous
//
#include <hip/hip_runtime.h>
#include <hip/hip_bf16.h>

#define B 32
#define H 128
#define L 4096
#define NC 32
#define NL 6
#define NCHUNK 128

typedef __hip_bfloat16 bf16;
typedef __attribute__((ext_vector_type(8))) short short8v;   // 8 bf16 (4 VGPR)
typedef __attribute__((ext_vector_type(4))) float floatx4;   // MFMA C/D

__device__ __forceinline__ float b2f(bf16 v) { return __bfloat162float(v); }
__device__ __forceinline__ float bu2f(unsigned int u) {
  union { unsigned int i; float f; } v; v.i = u << 16; return v.f;
}
// float -> bf16 bits via HW RNE convert
__device__ __forceinline__ unsigned short f2bs(float f) {
  bf16 b = __float2bfloat16(f);
  union { bf16 h; unsigned short s; } cv; cv.h = b; return cv.s;
}
// two floats -> packed bf16 dword (a low, b high) via v_cvt_pk_bf16_f32
__device__ __forceinline__ unsigned pack2(float a, float b) {
  union { __hip_bfloat162 h; unsigned u; } cv;
  cv.h = __float22bfloat162_rn(make_float2(a, b));
  return cv.u;
}

// Branch-free exact GELU: erf via Abramowitz-Stegun 7.1.26 (|eps|<=1.5e-7),
// v_rcp + v_exp instead of libm erff's divergent two-path rational (~50 slot-ops -> ~14).
__device__ __forceinline__ float gelu_exact(float v) {
  float ax = fabsf(v) * 0.70710678118654752f;                 // |v|/sqrt(2)
  float t  = __builtin_amdgcn_rcpf(fmaf(0.3275911f, ax, 1.f));
  float p  = t * fmaf(t, fmaf(t, fmaf(t, fmaf(t, 1.061405429f, -1.453152027f),
                                      1.421413741f), -0.284496736f), 0.254829592f);
  float e  = __builtin_amdgcn_exp2f(ax * ax * -1.4426950408889634f);  // exp(-x^2)
  float er = fmaf(-p, e, 1.f);                                // erf(|x|)
  return v * fmaf(0.5f, copysignf(er, v), 0.5f);              // v*0.5*(1+erf(v/sqrt2))
}

// ---------------- R5 fused front-end: encoder + s4d_prep + w_prep in ONE dispatch.
// The three are mutually independent; merging removes 2 launch gaps and lets the
// latency-bound prep overlap the write-bound encoder. Blocks branch uniformly:
//   [0, B*H)                encoder (R2 vectorized; R3 pooled zero-init)
//   [B*H, B*H+NL*H)         s4d_prep (R1 power-table version)
//   [B*H+NL*H, +768)        w_prep
__global__ __launch_bounds__(256) void fused_prep_kernel(
    const float* __restrict__ x, const float* __restrict__ enc_W,
    const float* __restrict__ enc_b, bf16* __restrict__ h, float* __restrict__ pooled,
    const float* __restrict__ out_W, unsigned short* __restrict__ Wb,
    const float* __restrict__ log_dt, const float* __restrict__ C_re,
    const float* __restrict__ C_im, const float* __restrict__ log_A_real,
    const float* __restrict__ A_imag, const float* __restrict__ Dp,
    unsigned short* __restrict__ Bg, float2* __restrict__ wTg) {
  __shared__ float2 cd_s[NC];
  __shared__ float K_s[32];
  __shared__ float2 P_s[NC][33];   // w_n^k, k=0..32
  int blk = blockIdx.x;
  int tid = threadIdx.x;

  if (blk < B * H) {   // ---------------- encoder ----------------
    int b = blk >> 7, ch = blk & 127;
    if (tid == 0) pooled[blk] = 0.f;   // (b*H+ch) == blk
    float w0 = enc_W[ch];
    float w1 = enc_W[H + ch];
    float bb = enc_b[ch];
    const float4* x0 = (const float4*)(x + (size_t)b * 2 * L);
    const float4* x1 = (const float4*)(x + (size_t)b * 2 * L + L);
    uint4* out = (uint4*)(h + ((size_t)b * H + ch) * L);
    for (int i = tid; i < L / 8; i += blockDim.x) {
      float4 a0 = x0[2 * i], a1 = x0[2 * i + 1];
      float4 c0 = x1[2 * i], c1 = x1[2 * i + 1];
      unsigned q0 = pack2(fmaf(a0.x, w0, fmaf(c0.x, w1, bb)), fmaf(a0.y, w0, fmaf(c0.y, w1, bb)));
      unsigned q1 = pack2(fmaf(a0.z, w0, fmaf(c0.z, w1, bb)), fmaf(a0.w, w0, fmaf(c0.w, w1, bb)));
      unsigned q2 = pack2(fmaf(a1.x, w0, fmaf(c1.x, w1, bb)), fmaf(a1.y, w0, fmaf(c1.y, w1, bb)));
      unsigned q3 = pack2(fmaf(a1.z, w0, fmaf(c1.z, w1, bb)), fmaf(a1.w, w0, fmaf(c1.w, w1, bb)));
      out[i] = make_uint4(q0, q1, q2, q3);
    }
    return;
  }

  if (blk >= B * H + NL * H) {   // ---------------- w_prep ----------------
    int idx = (blk - (B * H + NL * H)) * 256 + tid;
    if (idx >= NL * 2 * H * H) return;
    int l = idx / (2 * H * H);
    int rem = idx % (2 * H * H);
    float v = out_W[idx];
    unsigned short hi = f2bs(v);
    unsigned short lo = f2bs(v - bu2f(hi));
    Wb[(size_t)l * 65536 + rem] = hi;
    Wb[(size_t)l * 65536 + 32768 + rem] = lo;
    return;
  }

  // ---------------- s4d_prep (R1: power table, zero transcendentals in bulk) ----
  int lh = blk - B * H;
  int layer = lh >> 7, hh = lh & 127;
  if (tid < NC) {
    int n = tid, base = (layer * H + hh) * NC + n;
    float dt = expf(log_dt[layer * H + hh]);
    float Are = -expf(log_A_real[base]);
    float Aim = A_imag[base];
    float dre = dt * Are, dim = dt * Aim;
    float er = expf(dre);
    float wre = er * cosf(dim), wim = er * sinf(dim);
    float emre = wre - 1.f, emim = wim;   // expm1(dtA)
    float cre = C_re[base], cim = C_im[base];
    float nre = cre * emre - cim * emim, nim = cre * emim + cim * emre;
    float den = Are * Are + Aim * Aim;
    cd_s[n] = make_float2((nre * Are + nim * Aim) / den, (nim * Are - nre * Aim) / den);
    float e32 = expf(dre * 32.f);
    wTg[lh * NC + n] = make_float2(e32 * cosf(dim * 32.f), e32 * sinf(dim * 32.f));
    // power walk: P[n][k] = w^k (sequential cmul; |w|<1 so error doesn't amplify)
    P_s[n][0] = make_float2(1.f, 0.f);
    P_s[n][1] = make_float2(wre, wim);
    float rr = wre, ri = wim;
    #pragma unroll
    for (int k = 2; k <= 32; ++k) {
      float nr = rr * wre - ri * wim;
      ri = rr * wim + ri * wre;
      rr = nr;
      P_s[n][k] = make_float2(rr, ri);
    }
  }
  __syncthreads();
  if (tid < 32) {  // K[tau] = 2 sum_n Re(cd_n w_n^tau)
    float acc = 0.f;
    for (int n = 0; n < NC; ++n) {
      float2 p = P_s[n][tid];
      acc += cd_s[n].x * p.x - cd_s[n].y * p.y;
    }
    K_s[tid] = 2.f * acc;
  }
  __syncthreads();
  unsigned short* bb = Bg + (size_t)lh * 12288;
  float Dv = Dp[layer * H + hh];
  #pragma unroll
  for (int i = 0; i < 8; ++i) {     // VT: 2048 entries = Re/Im w^(31-t)
    int idx = tid + i * 256;
    int n2 = idx >> 5, t = idx & 31, n = n2 >> 1;
    float2 p = P_s[n][31 - t];
    float v = (n2 & 1) ? p.y : p.x;
    unsigned short hi = f2bs(v);
    unsigned short lo = f2bs(v - bu2f(hi));
    bb[n2 * 40 + t] = hi;
    bb[2560 + n2 * 40 + t] = lo;
  }
  #pragma unroll
  for (int i = 0; i < 4; ++i) {     // KT: 1024 entries
    int idx = tid + i * 256;
    int t = idx >> 5, m = idx & 31;
    float v = (m > t) ? 0.f : (K_s[t - m] + (m == t ? Dv : 0.f));
    unsigned short hi = f2bs(v);
    unsigned short lo = f2bs(v - bu2f(hi));
    bb[5120 + t * 40 + m] = hi;
    bb[6400 + t * 40 + m] = lo;
  }
  #pragma unroll
  for (int i = 0; i < 8; ++i) {     // WT: 2048 entries = ±2·{Re,Im}(cd_n w^(t+1))
    int idx = tid + i * 256;
    int t = idx >> 6, k = idx & 63, n = k >> 1;
    float2 p = P_s[n][t + 1];
    float cwr = cd_s[n].x * p.x - cd_s[n].y * p.y;
    float cwi = cd_s[n].x * p.y + cd_s[n].y * p.x;
    float v = (k & 1) ? -2.f * cwi : 2.f * cwr;
    unsigned short hi = f2bs(v);
    unsigned short lo = f2bs(v - bu2f(hi));
    bb[7680 + t * 72 + k] = hi;
    bb[9984 + t * 72 + k] = lo;
  }
}

// ---------------- S4D conv v7: no U staging (A-frags direct from global), GT/GE in
// S-row pads; LDS 37120 B -> 4 blocks/CU. Epilogue stages y through dead S_hi.
// R0: GELU via branch-free A&S erf (was libm erff — dominant VALU cost). ----------
__global__ __launch_bounds__(256, 4) void s4d_conv7_kernel(
    const bf16* __restrict__ u_g, bf16* __restrict__ y_g,
    const unsigned short* __restrict__ Bg, const float2* __restrict__ wTg) {
  static __shared__ char __align__(16) sm[37120];
  constexpr int O_SH = 0;       // scan re / packed hi: 128 rows x 144 B (cols 0..127 + 16 B pad)
  constexpr int O_SL = 18432;   // scan im / packed lo
  constexpr int O_WT = 36864;   // wT [32] float2 = 256 B
  // GT[i] lives in S_hi pad: O_SH + (i>>1)*144 + 128 + (i&1)*8   (i = g*32+n)
  // GE[i] lives in S_lo pad: O_SL + (i>>1)*144 + 128 + (i&1)*8

  int tid = threadIdx.x;
  int lane = tid & 63, wv = tid >> 6;
  int r15 = lane & 15, quad = lane >> 4;
  int bh = blockIdx.x, hh = bh & 127;
  const char* bg0 = (const char*)(Bg + (size_t)hh * 12288);
  const char* ug0 = (const char*)(u_g + (size_t)bh * L);

  if (tid < 32) *(float2*)(sm + O_WT + tid * 8) = wTg[hh * 32 + tid];

  // A-fragments direct from global (fully coalesced 16 B/lane within a 4 KB span)
  short8v aU0 = *(const short8v*)(ug0 + ((wv * 2 + 0) * 16 + r15) * 64 + quad * 16);
  short8v aU1 = *(const short8v*)(ug0 + ((wv * 2 + 1) * 16 + r15) * 64 + quad * 16);
  // V fragments from L2
  short8v bvh[4], bvl[4];
  #pragma unroll
  for (int nt = 0; nt < 4; ++nt) {
    bvh[nt] = *(const short8v*)(bg0 + 0    + (nt * 16 + r15) * 80 + quad * 16);
    bvl[nt] = *(const short8v*)(bg0 + 5120 + (nt * 16 + r15) * 80 + quad * 16);
  }

  // ---- phase P (no barrier needed before: all inputs are regs)
  floatx4 cp[2][4];
  #pragma unroll
  for (int mt = 0; mt < 2; ++mt)
    #pragma unroll
    for (int nt = 0; nt < 4; ++nt) cp[mt][nt] = (floatx4){0.f, 0.f, 0.f, 0.f};
  #pragma unroll
  for (int nt = 0; nt < 4; ++nt) {
    cp[0][nt] = __builtin_amdgcn_mfma_f32_16x16x32_bf16(aU0, bvh[nt], cp[0][nt], 0, 0, 0);
    cp[0][nt] = __builtin_amdgcn_mfma_f32_16x16x32_bf16(aU0, bvl[nt], cp[0][nt], 0, 0, 0);
    cp[1][nt] = __builtin_amdgcn_mfma_f32_16x16x32_bf16(aU1, bvh[nt], cp[1][nt], 0, 0, 0);
    cp[1][nt] = __builtin_amdgcn_mfma_f32_16x16x32_bf16(aU1, bvl[nt], cp[1][nt], 0, 0, 0);
  }
  #pragma unroll
  for (int mt = 0; mt < 2; ++mt)
    #pragma unroll
    for (int nt = 0; nt < 4; ++nt) {
      int n2 = nt * 16 + r15;
      int off = ((n2 & 1) ? O_SL : O_SH) + (n2 >> 1) * 4;
      #pragma unroll
      for (int rg = 0; rg < 4; ++rg) {
        int c = (wv * 2 + mt) * 16 + quad * 4 + rg;
        *(float*)(sm + off + c * 144) = cp[mt][nt][rg];
      }
    }
  __syncthreads();   // P stores + wT visible

  // ---- scan A: batched loads, recurrence in regs, prefixes HELD in regs
  int sg = tid >> 5, sn = tid & 31;
  float2 swt = *(const float2*)(sm + O_WT + sn * 8);
  float epr[16], epi[16];
  {
    float pr_[16], pi_[16];
    #pragma unroll
    for (int k = 0; k < 16; ++k) {
      pr_[k] = *(const float*)(sm + O_SH + (sg * 16 + k) * 144 + sn * 4);
      pi_[k] = *(const float*)(sm + O_SL + (sg * 16 + k) * 144 + sn * 4);
    }
    float rr = 0.f, ri = 0.f;
    #pragma unroll
    for (int k = 0; k < 16; ++k) {
      epr[k] = rr; epi[k] = ri;
      float nr = swt.x * rr - swt.y * ri + pr_[k];
      ri = swt.x * ri + swt.y * rr + pi_[k];
      rr = nr;
    }
    int i = sg * 32 + sn;
    *(float2*)(sm + O_SH + (i >> 1) * 144 + 128 + (i & 1) * 8) = make_float2(rr, ri);  // GT
  }
  __syncthreads();
  // ---- scan B: serial over 8 groups; wT^16 via 4 squarings
  if (tid < 32) {
    float2 wt = *(const float2*)(sm + O_WT + tid * 8);
    float w2r = wt.x * wt.x - wt.y * wt.y,   w2i = 2.f * wt.x * wt.y;
    float w4r = w2r * w2r - w2i * w2i,       w4i = 2.f * w2r * w2i;
    float w8r = w4r * w4r - w4i * w4i,       w8i = 2.f * w4r * w4i;
    float w16r = w8r * w8r - w8i * w8i,      w16i = 2.f * w8r * w8i;
    float rr = 0.f, ri = 0.f;
    for (int g = 0; g < 8; ++g) {
      int i = g * 32 + tid;
      *(float2*)(sm + O_SL + (i >> 1) * 144 + 128 + (i & 1) * 8) = make_float2(rr, ri);  // GE
      float2 gt = *(const float2*)(sm + O_SH + (i >> 1) * 144 + 128 + (i & 1) * 8);
      float nr = w16r * rr - w16i * ri + gt.x;
      ri = w16r * ri + w16i * rr + gt.y;
      rr = nr;
    }
  }
  __syncthreads();
  // ---- fixup: E[c] = prefix + wT^k * GE[g]; HW packed-cvt hi/lo write
  {
    int i = sg * 32 + sn;
    float2 ge = *(const float2*)(sm + O_SL + (i >> 1) * 144 + 128 + (i & 1) * 8);
    float ar = ge.x, ai = ge.y;   // wT^0 * GE
    #pragma unroll
    for (int k = 0; k < 16; ++k) {
      int c = sg * 16 + k;
      float er = epr[k] + ar;
      float ei = epi[k] + ai;
      unsigned uh = pack2(er, ei);
      *(unsigned*)(sm + O_SH + c * 144 + sn * 4) = uh;
      *(unsigned*)(sm + O_SL + c * 144 + sn * 4) =
          pack2(er - bu2f(uh & 0xffffu), ei - bu2f(uh >> 16));
      float nr = ar * swt.x - ai * swt.y;   // advance wT^k * GE
      ai = ar * swt.y + ai * swt.x;
      ar = nr;
    }
  }
  __syncthreads();

  // ---- Toeplitz + modal MFMAs (K/W frags direct from L2)
  floatx4 acc[2][2];
  #pragma unroll
  for (int mt = 0; mt < 2; ++mt)
    #pragma unroll
    for (int nt = 0; nt < 2; ++nt) acc[mt][nt] = (floatx4){0.f, 0.f, 0.f, 0.f};
  #pragma unroll
  for (int nt = 0; nt < 2; ++nt) {
    short8v kh = *(const short8v*)(bg0 + 10240 + (nt * 16 + r15) * 80 + quad * 16);
    short8v kl = *(const short8v*)(bg0 + 12800 + (nt * 16 + r15) * 80 + quad * 16);
    acc[0][nt] = __builtin_amdgcn_mfma_f32_16x16x32_bf16(aU0, kh, acc[0][nt], 0, 0, 0);
    acc[0][nt] = __builtin_amdgcn_mfma_f32_16x16x32_bf16(aU0, kl, acc[0][nt], 0, 0, 0);
    acc[1][nt] = __builtin_amdgcn_mfma_f32_16x16x32_bf16(aU1, kh, acc[1][nt], 0, 0, 0);
    acc[1][nt] = __builtin_amdgcn_mfma_f32_16x16x32_bf16(aU1, kl, acc[1][nt], 0, 0, 0);
  }
  #pragma unroll
  for (int ks = 0; ks < 2; ++ks) {
    short8v sh0 = *(const short8v*)(sm + O_SH + ((wv * 2 + 0) * 16 + r15) * 144 + ks * 64 + quad * 16);
    short8v sh1 = *(const short8v*)(sm + O_SH + ((wv * 2 + 1) * 16 + r15) * 144 + ks * 64 + quad * 16);
    short8v sl0 = *(const short8v*)(sm + O_SL + ((wv * 2 + 0) * 16 + r15) * 144 + ks * 64 + quad * 16);
    short8v sl1 = *(const short8v*)(sm + O_SL + ((wv * 2 + 1) * 16 + r15) * 144 + ks * 64 + quad * 16);
    #pragma unroll
    for (int nt = 0; nt < 2; ++nt) {
      short8v wh = *(const short8v*)(bg0 + 15360 + (nt * 16 + r15) * 144 + ks * 64 + quad * 16);
      short8v wl = *(const short8v*)(bg0 + 19968 + (nt * 16 + r15) * 144 + ks * 64 + quad * 16);
      acc[0][nt] = __builtin_amdgcn_mfma_f32_16x16x32_bf16(sh0, wh, acc[0][nt], 0, 0, 0);
      acc[0][nt] = __builtin_amdgcn_mfma_f32_16x16x32_bf16(sh0, wl, acc[0][nt], 0, 0, 0);
      acc[0][nt] = __builtin_amdgcn_mfma_f32_16x16x32_bf16(sl0, wh, acc[0][nt], 0, 0, 0);
      acc[1][nt] = __builtin_amdgcn_mfma_f32_16x16x32_bf16(sh1, wh, acc[1][nt], 0, 0, 0);
      acc[1][nt] = __builtin_amdgcn_mfma_f32_16x16x32_bf16(sh1, wl, acc[1][nt], 0, 0, 0);
      acc[1][nt] = __builtin_amdgcn_mfma_f32_16x16x32_bf16(sl1, wh, acc[1][nt], 0, 0, 0);
    }
  }
  __syncthreads();   // all S reads done; reuse S_hi base as y staging (8192 B)

  #pragma unroll
  for (int mt = 0; mt < 2; ++mt)
    #pragma unroll
    for (int nt = 0; nt < 2; ++nt)
      #pragma unroll
      for (int rg = 0; rg < 4; ++rg) {
        int c = (wv * 2 + mt) * 16 + quad * 4 + rg;
        int t = nt * 16 + r15;
        float v = gelu_exact(acc[mt][nt][rg]);
        *(unsigned short*)(sm + O_SH + (c * 32 + t) * 2) = f2bs(v);
      }
  __syncthreads();
  {
    uint4* yo = (uint4*)(y_g + (size_t)bh * L);
    #pragma unroll
    for (int r = 0; r < 2; ++r) {
      int idx = tid + r * 256;
      yo[idx] = *(const uint4*)(sm + O_SH + idx * 16);
    }
  }
}

// ------- glu_ln v14 = v11 + R7: hoist the 16 loop-invariant Wb weight fragments
// (wa/wg x 2i x 4ks) into registers before the t-loop — v11 re-issued them from L2
// every tile (48 redundant loads/thread, VGPR_Count=60 proved no compiler hoist).
// Also hoists lg/lb. Structure (proven v11 schedule) unchanged. -------
__global__ __launch_bounds__(256, 2) void glu_ln14_kernel(
    const unsigned short* __restrict__ y_g, unsigned short* __restrict__ h_g,
    const unsigned short* __restrict__ Wb,  // layer: [hi 256x128] shorts
    const float* __restrict__ ob, const float* __restrict__ lg,
    const float* __restrict__ lb, float* __restrict__ pooled) {
  static __shared__ char __align__(16) sm[36864];
  constexpr int O_Y = 0;        // y transposed [64 pos][136 ch-shorts] = 17408 B (row 272 B)
  constexpr int O_H = 17408;    // h natural [128 ch][68 pos-shorts] = 17408 B; z aliases in-place
  constexpr int O_P = 34816;    // LN partials [4 waves][64 pos] float2 = 2048 B

  int tid = threadIdx.x;
  int wv = tid >> 6, lane = tid & 63, r15 = lane & 15, quad = lane >> 4;
  int b = blockIdx.x >> 4, seg = blockIdx.x & 15;

  float ba[2][4], bgl[2][4];
  #pragma unroll
  for (int i = 0; i < 2; ++i) {
    int ch0 = (2 * wv + i) * 16 + quad * 4;
    #pragma unroll
    for (int rg = 0; rg < 4; ++rg) {
      ba[i][rg]  = ob[ch0 + rg];
      bgl[i][rg] = ob[128 + ch0 + rg];
    }
  }
  // R7: weight fragments in registers (loop-invariant across the 4 tiles)
  short8v wfa[2][4], wfg[2][4];
  #pragma unroll
  for (int i = 0; i < 2; ++i) {
    const unsigned short* wa = Wb + (size_t)((2 * wv + i) * 16 + r15) * 128 + quad * 8;
    const unsigned short* wg = Wb + (size_t)((8 + 2 * wv + i) * 16 + r15) * 128 + quad * 8;
    #pragma unroll
    for (int ks = 0; ks < 4; ++ks) {
      wfa[i][ks] = *(const short8v*)(wa + ks * 32);
      wfg[i][ks] = *(const short8v*)(wg + ks * 32);
    }
  }
  // R7: LN affine params hoisted (phase D re-loaded them per tile)
  float gg_r = lg[tid >> 1], bb_r = lb[tid >> 1];

  float psum = 0.f;   // R3: fused-pool accumulator (channel tid>>1, this thread's 128 positions)

  for (int t = 0; t < 4; ++t) {
    int l0 = seg * 256 + t * 64;
    {
      int k = tid >> 1, half = tid & 1;
      const uint4* src = (const uint4*)(y_g + ((size_t)(b * H + k)) * L + l0 + half * 32);
      unsigned short sarr[32];
      uint4* sp = (uint4*)sarr;
      sp[0] = src[0]; sp[1] = src[1]; sp[2] = src[2]; sp[3] = src[3];
      #pragma unroll
      for (int j = 0; j < 32; ++j)
        *(unsigned short*)(sm + O_Y + (half * 32 + j) * 272 + k * 2) = sarr[j];
    }
    {
      #pragma unroll
      for (int i = 0; i < 4; ++i) {
        int id = tid + i * 256;           // 0..1023
        int ch = id >> 3, part = id & 7;
        uint4 v = *(const uint4*)(h_g + ((size_t)(b * H + ch)) * L + l0 + part * 8);
        *(uint4*)(sm + O_H + ch * 136 + part * 16) = v;
      }
    }
    __syncthreads();   // A

    float s1[4] = {0.f, 0.f, 0.f, 0.f}, s2[4] = {0.f, 0.f, 0.f, 0.f};
    #pragma unroll
    for (int pt = 0; pt < 4; ++pt) {
      short8v bf[4];
      #pragma unroll
      for (int ks = 0; ks < 4; ++ks)
        bf[ks] = *(const short8v*)(sm + O_Y + (pt * 16 + r15) * 272 + ks * 64 + quad * 16);
      int pos = pt * 16 + r15;
      #pragma unroll
      for (int i = 0; i < 2; ++i) {
        int ch0 = (2 * wv + i) * 16 + quad * 4;
        floatx4 acca = (floatx4){0.f, 0.f, 0.f, 0.f};
        floatx4 accg = (floatx4){0.f, 0.f, 0.f, 0.f};
        #pragma unroll
        for (int ks = 0; ks < 4; ++ks) {
          acca = __builtin_amdgcn_mfma_f32_16x16x32_bf16(wfa[i][ks], bf[ks], acca, 0, 0, 0);
          accg = __builtin_amdgcn_mfma_f32_16x16x32_bf16(wfg[i][ks], bf[ks], accg, 0, 0, 0);
        }
        #pragma unroll
        for (int rg = 0; rg < 4; ++rg) {
          float a = acca[rg] + ba[i][rg];
          float g = accg[rg] + bgl[i][rg];
          float eg = __builtin_amdgcn_exp2f(g * -1.4426950408889634f);
          float zz = a * __builtin_amdgcn_rcpf(1.f + eg);
          char* slot = sm + O_H + (ch0 + rg) * 136 + pos * 2;
          zz += bu2f(*(const unsigned short*)slot);   // residual read
          s1[pt] += zz;
          s2[pt] += zz * zz;
          *(unsigned short*)slot = f2bs(zz);          // z write, same slot, same lane
        }
      }
    }
    #pragma unroll
    for (int pt = 0; pt < 4; ++pt) {
      s1[pt] += __shfl_xor(s1[pt], 16, 64); s1[pt] += __shfl_xor(s1[pt], 32, 64);
      s2[pt] += __shfl_xor(s2[pt], 16, 64); s2[pt] += __shfl_xor(s2[pt], 32, 64);
    }
    if (quad == 0) {
      #pragma unroll
      for (int pt = 0; pt < 4; ++pt)
        *(float2*)(sm + O_P + (wv * 64 + pt * 16 + r15) * 8) = make_float2(s1[pt], s2[pt]);
    }
    __syncthreads();   // B

    if (tid < 64) {
      float a1 = 0.f, a2 = 0.f;
      #pragma unroll
      for (int w = 0; w < 4; ++w) {
        float2 p = *(const float2*)(sm + O_P + (w * 64 + tid) * 8);
        a1 += p.x; a2 += p.y;
      }
      float m = a1 * (1.f / H);
      float var = a2 * (1.f / H) - m * m;
      if (var < 0.f) var = 0.f;
      *(float2*)(sm + O_P + tid * 8) = make_float2(m, rsqrtf(var + 1e-5f));
    }
    __syncthreads();   // C

    {
      int ch = tid >> 1, half = tid & 1;
      unsigned outw[16];
      #pragma unroll
      for (int j = 0; j < 16; ++j) {
        int p0 = half * 32 + 2 * j;
        float z0 = bu2f(*(const unsigned short*)(sm + O_H + ch * 136 + p0 * 2));
        float z1 = bu2f(*(const unsigned short*)(sm + O_H + ch * 136 + p0 * 2 + 2));
        float2 m0 = *(const float2*)(sm + O_P + p0 * 8);
        float2 m1 = *(const float2*)(sm + O_P + (p0 + 1) * 8);
        float o0 = (z0 - m0.x) * m0.y * gg_r + bb_r;
        float o1 = (z1 - m1.x) * m1.y * gg_r + bb_r;
        psum += o0 + o1;
        outw[j] = pack2(o0, o1);
      }
      uint4* dst = (uint4*)(h_g + ((size_t)(b * H + ch)) * L + l0 + half * 32);
      #pragma unroll
      for (int j = 0; j < 4; ++j)
        dst[j] = *(const uint4*)(&outw[j * 4]);
    }
    __syncthreads();   // D
  }

  if (pooled != nullptr) {   // final layer only: fused mean-pool partials
    psum += __shfl_xor(psum, 1, 64);          // combine the two halves of this channel
    if ((tid & 1) == 0)
      atomicAdd(pooled + b * H + (tid >> 1), psum);
  }
}

__global__ void head_kernel(const float* __restrict__ pooled,
                            const float* __restrict__ head_W,
                            const float* __restrict__ head_b,
                            float* __restrict__ out) {
  int tid = threadIdx.x;
  if (tid >= B * 2) return;
  int b = tid >> 1, o = tid & 1;
  float acc = 0.f;
  for (int ch = 0; ch < H; ++ch)
    acc += pooled[b * H + ch] * head_W[ch * 2 + o];
  out[tid] = head_b[o] + acc * (1.f / L);   // pooled holds SUM over L (fused pool)
}

extern "C" void kernel_launch(void* const* d_in, const int* in_sizes, int n_in,
                              void* d_out, int out_size, void* d_ws, size_t ws_size,
                              hipStream_t stream) {
  const float* x          = (const float*)d_in[0];
  const float* enc_W      = (const float*)d_in[1];
  const float* enc_b      = (const float*)d_in[2];
  const float* log_dt     = (const float*)d_in[3];
  const float* C_re       = (const float*)d_in[4];
  const float* C_im       = (const float*)d_in[5];
  const float* log_A_real = (const float*)d_in[6];
  const float* A_imag     = (const float*)d_in[7];
  const float* Dp         = (const float*)d_in[8];
  const float* out_W      = (const float*)d_in[9];
  const float* out_b      = (const float*)d_in[10];
  const float* ln_g       = (const float*)d_in[11];
  const float* ln_b       = (const float*)d_in[12];
  const float* head_W     = (const float*)d_in[13];
  const float* head_b     = (const float*)d_in[14];

  // ws (~84.6 MB): hbuf bf16 32MB | ybuf bf16 32MB | Wb 1.5MB | pooled 16KB |
  //                Bg (all layers) 18.9MB | wTg (all layers) 196KB
  bf16* hbuf = (bf16*)d_ws;
  bf16* ybuf = hbuf + (size_t)B * H * L;
  unsigned short* Wb = (unsigned short*)(ybuf + (size_t)B * H * L);
  float* pooled = (float*)(Wb + (size_t)NL * 65536);
  unsigned short* Bg = (unsigned short*)(pooled + B * H);
  float2* wTg = (float2*)(Bg + (size_t)NL * H * 12288);

  // R5: one fused front-end dispatch (encoder + s4d_prep + w_prep)
  int nwp = (NL * 2 * H * H + 255) / 256;
  fused_prep_kernel<<<B * H + NL * H + nwp, 256, 0, stream>>>(
      x, enc_W, enc_b, hbuf, pooled, out_W, Wb,
      log_dt, C_re, C_im, log_A_real, A_imag, Dp, Bg, wTg);

  for (int layer = 0; layer < NL; ++layer) {
    s4d_conv7_kernel<<<B * H, 256, 0, stream>>>(
        hbuf, ybuf, Bg + (size_t)layer * H * 12288, wTg + (size_t)layer * H * NC);
    glu_ln14_kernel<<<B * 16, 256, 0, stream>>>(
        (const unsigned short*)ybuf, (unsigned short*)hbuf,
        Wb + (size_t)layer * 65536, out_b + layer * 2 * H,
        ln_g + layer * H, ln_b + layer * H,
        (layer == NL - 1) ? pooled : nullptr);
  }

  head_kernel<<<1, 64, 0, stream>>>(pooled, head_W, head_b, (float*)d_out);
}